// Round 7
// baseline (223.593 us; speedup 1.0000x reference)
//
#include <hip/hip_runtime.h>
#include <hip/hip_bf16.h>
#include <math.h>

// ADC LUT-quantization kernel, round 6.
// out = floor(interp1d(lut_x, lut_y, clip(x/8*lut_x[-1], ...)) * 256/max(lut_y)) * 8/256
//
// R6 vs R5 (208.9us = 5.14 TB/s, 82% of copy ceiling):
//  - software-pipelined main loop: prefetch the NEXT pair of f32x4 before
//    computing/storing the current pair -> load-to-use distance = 1 full
//    iteration (was ~0), hiding HBM+LDS latency inside each wave.
//  - live set: 4 f32x4 + temps ~= 60 VGPR, safely under the 64-VGPR
//    occupancy cliff (R4's 8x unroll crossed it: 229us).
//  - unchanged: nt loads/stores, clamp-free index guess, affine (A,B)
//    float2 LDS table with scale folded in.

#define LUT_MAX 4096
#define BLOCK 512

typedef float f32x4 __attribute__((ext_vector_type(4)));

__global__ __launch_bounds__(BLOCK) void adc_fused_kernel(
    const float* __restrict__ x,
    const float* __restrict__ lut_x,
    const float* __restrict__ lut_y,
    float* __restrict__ out,
    long long n, int lutN)
{
    __shared__ float2 sAB[LUT_MAX];      // (A_i, B_i) per segment
    __shared__ float wmax[BLOCK / 64];

    const int tid = threadIdx.x;

    // ---- phase 1: out_max = max(lut_y) (block-redundant, trivial cost) ----
    float lm = -INFINITY;
    for (int i = tid; i < lutN; i += BLOCK)
        lm = fmaxf(lm, lut_y[i]);
    #pragma unroll
    for (int o = 32; o > 0; o >>= 1)
        lm = fmaxf(lm, __shfl_down(lm, o, 64));
    if ((tid & 63) == 0) wmax[tid >> 6] = lm;
    __syncthreads();
    float out_max = wmax[0];
    #pragma unroll
    for (int w = 1; w < BLOCK / 64; ++w)
        out_max = fmaxf(out_max, wmax[w]);

    const float scale  = 256.0f / out_max;           // full_scale / adc_out_max
    const float in_min = lut_x[0];
    const float in_max = lut_x[lutN - 1];
    // shrink so (in_max - in_min)*guess_scale < lutN-1 strictly -> no idx clamp
    const float guess_scale = ((float)(lutN - 1) / (in_max - in_min))
                              * (1.0f - 3.8147e-6f /* ~2^-18 */);
    const float guess_bias  = -in_min * guess_scale;

    // ---- phase 2: build fused affine table (re-read lut from L2) ----
    for (int i = tid; i < lutN - 1; i += BLOCK) {
        float x0 = lut_x[i], x1 = lut_x[i + 1];
        float y0 = lut_y[i], y1 = lut_y[i + 1];
        float slope = (y1 - y0) / (x1 - x0);
        sAB[i] = make_float2(scale * (y0 - x0 * slope), scale * slope);
    }
    __syncthreads();

    const float xscale = 0.125f * in_max;  // x * (1/8) * lut_x[-1]

    auto quant = [&](float xin) -> float {
        float v  = fminf(fmaxf(xin * xscale, in_min), in_max);  // v_med3
        int  idx = (int)fmaf(v, guess_scale, guess_bias);       // no clamp
        float2 ab = sAB[idx];
        return floorf(fmaf(v, ab.y, ab.x)) * 0.03125f;          // * 8/256
    };

    auto quant4 = [&](f32x4 a) -> f32x4 {
        f32x4 r;
        r.x = quant(a.x); r.y = quant(a.y); r.z = quant(a.z); r.w = quant(a.w);
        return r;
    };

    // ---- main loop: 2-wide, software-pipelined (prefetch next pair) ----
    const long long n4 = n >> 2;
    const f32x4* __restrict__ x4 = (const f32x4*)x;
    f32x4* __restrict__ o4 = (f32x4*)out;
    const long long g = (long long)gridDim.x * BLOCK;
    long long i = (long long)blockIdx.x * BLOCK + tid;

    if (i + g < n4) {
        f32x4 A0 = __builtin_nontemporal_load(&x4[i]);
        f32x4 A1 = __builtin_nontemporal_load(&x4[i + g]);
        for (; i + 3 * g < n4; i += 2 * g) {
            f32x4 B0 = __builtin_nontemporal_load(&x4[i + 2 * g]);
            f32x4 B1 = __builtin_nontemporal_load(&x4[i + 3 * g]);
            __builtin_nontemporal_store(quant4(A0), &o4[i]);
            __builtin_nontemporal_store(quant4(A1), &o4[i + g]);
            A0 = B0;
            A1 = B1;
        }
        __builtin_nontemporal_store(quant4(A0), &o4[i]);
        __builtin_nontemporal_store(quant4(A1), &o4[i + g]);
        i += 2 * g;
    }
    for (; i < n4; i += g) {
        f32x4 a = __builtin_nontemporal_load(&x4[i]);
        __builtin_nontemporal_store(quant4(a), &o4[i]);
    }

    // ---- scalar tail (n not multiple of 4) ----
    for (long long j = (n4 << 2) + (long long)blockIdx.x * BLOCK + tid;
         j < n; j += g) {
        out[j] = quant(x[j]);
    }
}

extern "C" void kernel_launch(void* const* d_in, const int* in_sizes, int n_in,
                              void* d_out, int out_size, void* d_ws, size_t ws_size,
                              hipStream_t stream) {
    const float* x     = (const float*)d_in[0];
    const float* lut_x = (const float*)d_in[1];
    const float* lut_y = (const float*)d_in[2];
    float* out = (float*)d_out;

    const long long n = (long long)out_size;
    const int lutN = in_sizes[1];

    long long n4 = n >> 2;
    long long want = (n4 + BLOCK - 1) / BLOCK;
    int blocks = (int)(want < 1024 ? want : 1024);  // 4 blocks/CU (LDS-limited)
    if (blocks < 1) blocks = 1;

    adc_fused_kernel<<<blocks, BLOCK, 0, stream>>>(x, lut_x, lut_y, out, n, lutN);
}

// Round 8
// 212.423 us; speedup vs baseline: 1.0526x; 1.0526x over previous
//
#include <hip/hip_runtime.h>
#include <hip/hip_bf16.h>
#include <hip/hip_fp16.h>
#include <math.h>

// ADC LUT-quantization kernel, round 7.
// out = floor(interp1d(lut_x, lut_y, clip(x/8*lut_x[-1], ...)) * 256/max(lut_y)) * 8/256
//
// R7 vs R5 (208.9us = 5.14 TB/s): attack the random-LDS-gather conflicts.
//  - per-segment affine (A,B) packed as fp16x2 in ONE b32 word: random b32
//    gather spreads 64 lanes over 32 banks (~5 cyc/wave) vs b64 over 16
//    bank-pairs (~13 cyc/wave). R1 measured 5.8e7 conflict cycles (~40% of
//    the 500K-cycle/CU budget at 208us).
//  - precision: |A|,|B*v| <= ~260, fp16 rel eps 4.9e-4 -> <=0.13 code
//    perturbation -> floor flips <=1 code = 0.03125 << 0.16 threshold.
//    (Steep first cells: B large but B*v small there -> ~0.003 codes.)
//  - unchanged: 4x strided unroll, nt loads/stores, clamp-free index guess.

#define LUT_MAX 4096
#define BLOCK 512

typedef float f32x4 __attribute__((ext_vector_type(4)));

__global__ __launch_bounds__(BLOCK) void adc_fused_kernel(
    const float* __restrict__ x,
    const float* __restrict__ lut_x,
    const float* __restrict__ lut_y,
    float* __restrict__ out,
    long long n, int lutN)
{
    __shared__ __half2 sAB[LUT_MAX];     // (A_i, B_i) per segment, fp16x2
    __shared__ float wmax[BLOCK / 64];

    const int tid = threadIdx.x;

    // ---- phase 1: out_max = max(lut_y) (block-redundant, trivial cost) ----
    float lm = -INFINITY;
    for (int i = tid; i < lutN; i += BLOCK)
        lm = fmaxf(lm, lut_y[i]);
    #pragma unroll
    for (int o = 32; o > 0; o >>= 1)
        lm = fmaxf(lm, __shfl_down(lm, o, 64));
    if ((tid & 63) == 0) wmax[tid >> 6] = lm;
    __syncthreads();
    float out_max = wmax[0];
    #pragma unroll
    for (int w = 1; w < BLOCK / 64; ++w)
        out_max = fmaxf(out_max, wmax[w]);

    const float scale  = 256.0f / out_max;           // full_scale / adc_out_max
    const float in_min = lut_x[0];
    const float in_max = lut_x[lutN - 1];
    // shrink so (in_max - in_min)*guess_scale < lutN-1 strictly -> no idx clamp
    const float guess_scale = ((float)(lutN - 1) / (in_max - in_min))
                              * (1.0f - 3.8147e-6f /* ~2^-18 */);
    const float guess_bias  = -in_min * guess_scale;

    // ---- phase 2: build fused affine table (re-read lut from L2) ----
    for (int i = tid; i < lutN - 1; i += BLOCK) {
        float x0 = lut_x[i], x1 = lut_x[i + 1];
        float y0 = lut_y[i], y1 = lut_y[i + 1];
        float slope = (y1 - y0) / (x1 - x0);
        sAB[i] = __floats2half2_rn(scale * (y0 - x0 * slope), scale * slope);
    }
    __syncthreads();

    const float xscale = 0.125f * in_max;  // x * (1/8) * lut_x[-1]

    auto quant = [&](float xin) -> float {
        float v  = fminf(fmaxf(xin * xscale, in_min), in_max);  // v_med3
        int  idx = (int)fmaf(v, guess_scale, guess_bias);       // no clamp
        float2 ab = __half22float2(sAB[idx]);                   // 1x b32 gather
        return floorf(fmaf(v, ab.y, ab.x)) * 0.03125f;          // * 8/256
    };

    auto quant4 = [&](f32x4 a) -> f32x4 {
        f32x4 r;
        r.x = quant(a.x); r.y = quant(a.y); r.z = quant(a.z); r.w = quant(a.w);
        return r;
    };

    // ---- main loop: grid-stride f32x4, 4x strided unroll, nontemporal ----
    const long long n4 = n >> 2;
    const f32x4* __restrict__ x4 = (const f32x4*)x;
    f32x4* __restrict__ o4 = (f32x4*)out;
    const long long gstride = (long long)gridDim.x * BLOCK;
    long long i = (long long)blockIdx.x * BLOCK + tid;

    for (; i + 3 * gstride < n4; i += 4 * gstride) {
        f32x4 a0 = __builtin_nontemporal_load(&x4[i]);
        f32x4 a1 = __builtin_nontemporal_load(&x4[i + gstride]);
        f32x4 a2 = __builtin_nontemporal_load(&x4[i + 2 * gstride]);
        f32x4 a3 = __builtin_nontemporal_load(&x4[i + 3 * gstride]);
        f32x4 r0 = quant4(a0);
        f32x4 r1 = quant4(a1);
        f32x4 r2 = quant4(a2);
        f32x4 r3 = quant4(a3);
        __builtin_nontemporal_store(r0, &o4[i]);
        __builtin_nontemporal_store(r1, &o4[i + gstride]);
        __builtin_nontemporal_store(r2, &o4[i + 2 * gstride]);
        __builtin_nontemporal_store(r3, &o4[i + 3 * gstride]);
    }
    for (; i < n4; i += gstride) {
        f32x4 a = __builtin_nontemporal_load(&x4[i]);
        __builtin_nontemporal_store(quant4(a), &o4[i]);
    }

    // ---- scalar tail (n not multiple of 4) ----
    for (long long j = (n4 << 2) + (long long)blockIdx.x * BLOCK + tid;
         j < n; j += gstride) {
        out[j] = quant(x[j]);
    }
}

extern "C" void kernel_launch(void* const* d_in, const int* in_sizes, int n_in,
                              void* d_out, int out_size, void* d_ws, size_t ws_size,
                              hipStream_t stream) {
    const float* x     = (const float*)d_in[0];
    const float* lut_x = (const float*)d_in[1];
    const float* lut_y = (const float*)d_in[2];
    float* out = (float*)d_out;

    const long long n = (long long)out_size;
    const int lutN = in_sizes[1];

    long long n4 = n >> 2;
    long long want = (n4 + BLOCK - 1) / BLOCK;
    int blocks = (int)(want < 1024 ? want : 1024);  // 4 blocks/CU (thread cap)
    if (blocks < 1) blocks = 1;

    adc_fused_kernel<<<blocks, BLOCK, 0, stream>>>(x, lut_x, lut_y, out, n, lutN);
}

// Round 9
// 209.186 us; speedup vs baseline: 1.0689x; 1.0155x over previous
//
#include <hip/hip_runtime.h>
#include <hip/hip_bf16.h>
#include <math.h>

// ADC LUT-quantization kernel, FINAL (= round-5 best: 208.9us, 5.15 TB/s).
// out = floor(interp1d(lut_x, lut_y, clip(x/8*lut_x[-1], ...)) * 256/max(lut_y)) * 8/256
//
// Diagnostic history:
//  R0 334us naive-interp -> R1 225us (affine LDS table, occupancy fix)
//  -> R3 208us (nt loads/stores + 4x burst unroll).
//  R4 8x unroll: 229us (VGPR/occupancy cliff). R6 SW-pipeline: 223us
//  (less MLP). R5 clamp-free: flat (not VALU-bound). R7 fp16 b32 gather:
//  flat (not LDS-bound). => memory-system structural ceiling at 82% of
//  the 6.29 TB/s measured copy BW, with a dependent random LDS gather in
//  every load->store chain. Terminal kernel.

#define LUT_MAX 4096
#define BLOCK 512

typedef float f32x4 __attribute__((ext_vector_type(4)));

__global__ __launch_bounds__(BLOCK) void adc_fused_kernel(
    const float* __restrict__ x,
    const float* __restrict__ lut_x,
    const float* __restrict__ lut_y,
    float* __restrict__ out,
    long long n, int lutN)
{
    __shared__ float2 sAB[LUT_MAX];      // (A_i, B_i) per segment
    __shared__ float wmax[BLOCK / 64];

    const int tid = threadIdx.x;

    // ---- phase 1: out_max = max(lut_y) (block-redundant, trivial cost) ----
    float lm = -INFINITY;
    for (int i = tid; i < lutN; i += BLOCK)
        lm = fmaxf(lm, lut_y[i]);
    #pragma unroll
    for (int o = 32; o > 0; o >>= 1)
        lm = fmaxf(lm, __shfl_down(lm, o, 64));
    if ((tid & 63) == 0) wmax[tid >> 6] = lm;
    __syncthreads();
    float out_max = wmax[0];
    #pragma unroll
    for (int w = 1; w < BLOCK / 64; ++w)
        out_max = fmaxf(out_max, wmax[w]);

    const float scale  = 256.0f / out_max;           // full_scale / adc_out_max
    const float in_min = lut_x[0];
    const float in_max = lut_x[lutN - 1];
    // shrink so (in_max - in_min)*guess_scale < lutN-1 strictly -> no idx clamp
    const float guess_scale = ((float)(lutN - 1) / (in_max - in_min))
                              * (1.0f - 3.8147e-6f /* ~2^-18 */);
    const float guess_bias  = -in_min * guess_scale;

    // ---- phase 2: build fused affine table (re-read lut from L2) ----
    for (int i = tid; i < lutN - 1; i += BLOCK) {
        float x0 = lut_x[i], x1 = lut_x[i + 1];
        float y0 = lut_y[i], y1 = lut_y[i + 1];
        float slope = (y1 - y0) / (x1 - x0);
        sAB[i] = make_float2(scale * (y0 - x0 * slope), scale * slope);
    }
    __syncthreads();

    const float xscale = 0.125f * in_max;  // x * (1/8) * lut_x[-1]

    auto quant = [&](float xin) -> float {
        float v  = fminf(fmaxf(xin * xscale, in_min), in_max);  // v_med3
        int  idx = (int)fmaf(v, guess_scale, guess_bias);       // no clamp
        float2 ab = sAB[idx];
        return floorf(fmaf(v, ab.y, ab.x)) * 0.03125f;          // * 8/256
    };

    auto quant4 = [&](f32x4 a) -> f32x4 {
        f32x4 r;
        r.x = quant(a.x); r.y = quant(a.y); r.z = quant(a.z); r.w = quant(a.w);
        return r;
    };

    // ---- main loop: grid-stride f32x4, 4x strided unroll, nontemporal ----
    const long long n4 = n >> 2;
    const f32x4* __restrict__ x4 = (const f32x4*)x;
    f32x4* __restrict__ o4 = (f32x4*)out;
    const long long gstride = (long long)gridDim.x * BLOCK;
    long long i = (long long)blockIdx.x * BLOCK + tid;

    for (; i + 3 * gstride < n4; i += 4 * gstride) {
        f32x4 a0 = __builtin_nontemporal_load(&x4[i]);
        f32x4 a1 = __builtin_nontemporal_load(&x4[i + gstride]);
        f32x4 a2 = __builtin_nontemporal_load(&x4[i + 2 * gstride]);
        f32x4 a3 = __builtin_nontemporal_load(&x4[i + 3 * gstride]);
        f32x4 r0 = quant4(a0);
        f32x4 r1 = quant4(a1);
        f32x4 r2 = quant4(a2);
        f32x4 r3 = quant4(a3);
        __builtin_nontemporal_store(r0, &o4[i]);
        __builtin_nontemporal_store(r1, &o4[i + gstride]);
        __builtin_nontemporal_store(r2, &o4[i + 2 * gstride]);
        __builtin_nontemporal_store(r3, &o4[i + 3 * gstride]);
    }
    for (; i < n4; i += gstride) {
        f32x4 a = __builtin_nontemporal_load(&x4[i]);
        __builtin_nontemporal_store(quant4(a), &o4[i]);
    }

    // ---- scalar tail (n not multiple of 4) ----
    for (long long j = (n4 << 2) + (long long)blockIdx.x * BLOCK + tid;
         j < n; j += gstride) {
        out[j] = quant(x[j]);
    }
}

extern "C" void kernel_launch(void* const* d_in, const int* in_sizes, int n_in,
                              void* d_out, int out_size, void* d_ws, size_t ws_size,
                              hipStream_t stream) {
    const float* x     = (const float*)d_in[0];
    const float* lut_x = (const float*)d_in[1];
    const float* lut_y = (const float*)d_in[2];
    float* out = (float*)d_out;

    const long long n = (long long)out_size;
    const int lutN = in_sizes[1];

    long long n4 = n >> 2;
    long long want = (n4 + BLOCK - 1) / BLOCK;
    int blocks = (int)(want < 1024 ? want : 1024);  // 4 blocks/CU (thread cap)
    if (blocks < 1) blocks = 1;

    adc_fused_kernel<<<blocks, BLOCK, 0, stream>>>(x, lut_x, lut_y, out, n, lutN);
}